// Round 11
// baseline (1423.371 us; speedup 1.0000x reference)
//
#include <hip/hip_runtime.h>
#include <hip/hip_cooperative_groups.h>

namespace cg = cooperative_groups;

#define N_NODES 50000
#define N_EDGES 800000
#define FDIM 128
#define NROWS 100000   // B * N_NODES
#define BN_EPS 1e-5f
#define SCAN_BLOCKS 196   // ceil(50000 / 256)

typedef unsigned short ushort_t;
typedef unsigned int uint_t;
typedef __attribute__((ext_vector_type(8))) short bf16x8;   // MFMA A/B frag
typedef __attribute__((ext_vector_type(4))) float f32x4;    // MFMA C/D frag

// round-to-nearest-even fp32 -> bf16
__device__ inline ushort_t f2bf(float f) {
    uint_t x = __float_as_uint(f);
    x += 0x7fffu + ((x >> 16) & 1u);
    return (ushort_t)(x >> 16);
}
__device__ inline float4 bf4_to_f4(ushort4 u) {
    float4 f;
    f.x = __uint_as_float((uint_t)u.x << 16);
    f.y = __uint_as_float((uint_t)u.y << 16);
    f.z = __uint_as_float((uint_t)u.z << 16);
    f.w = __uint_as_float((uint_t)u.w << 16);
    return f;
}
// split-bf16: f = hi + lo with |err| ~ 2^-18 |f|
__device__ inline void split4(float4 v, bf16x8& hi, bf16x8& lo, int base) {
    float f[4] = {v.x, v.y, v.z, v.w};
    #pragma unroll
    for (int t = 0; t < 4; ++t) {
        ushort_t h = f2bf(f[t]);
        float fh = __uint_as_float((uint_t)h << 16);
        ushort_t l = f2bf(f[t] - fh);
        hi[base + t] = (short)h;
        lo[base + t] = (short)l;
    }
}

// ---------------- Cooperative CSR build: wsplit+zero / hist / scan / bucket ----------------
__global__ __launch_bounds__(256, 4) void csr_build_coop(
        const float* __restrict__ W1, const float* __restrict__ W2,
        const int* __restrict__ row, const int* __restrict__ col,
        ushort_t* __restrict__ wt, int* __restrict__ cnt, float* __restrict__ stats,
        int* __restrict__ offsets, int* __restrict__ cursor,
        int* __restrict__ partials, int* __restrict__ srcbuf) {
    cg::grid_group grid = cg::this_grid();
    __shared__ int ws[4];
    int tid = threadIdx.x, bid = blockIdx.x;
    int gid = bid * 256 + tid;                     // 0..262143
    int lane = tid & 63, wid = tid >> 6;
    int gstride = gridDim.x * 256;

    // P0: zero cnt + stats, W split/transpose (hi/lo bf16 planes, Wt[n][k])
    for (int i = gid; i < N_NODES; i += gstride) cnt[i] = 0;
    if (gid < 512) stats[gid] = 0.f;
    if (gid < 32768) {
        int which = gid >> 14;
        int e = gid & 16383;                       // e = k*128 + n (coalesced read)
        int k = e >> 7, n = e & 127;
        float f = (which ? W2 : W1)[e];
        ushort_t h = f2bf(f);
        float fh = __uint_as_float((uint_t)h << 16);
        ushort_t l = f2bf(f - fh);
        size_t base = (size_t)which * 32768;
        wt[base + n * 128 + k] = h;
        wt[base + 16384 + n * 128 + k] = l;
    }
    grid.sync();

    // P1: histogram of destinations
    for (int e = gid; e < N_EDGES; e += gstride) atomicAdd(&cnt[col[e]], 1);
    grid.sync();

    // P2: per-chunk sums (blocks < 196)
    if (bid < SCAN_BLOCKS) {
        int i = bid * 256 + tid;
        int v = (i < N_NODES) ? cnt[i] : 0;
        #pragma unroll
        for (int d = 32; d > 0; d >>= 1) v += __shfl_xor(v, d);
        if (lane == 0) ws[wid] = v;
        __syncthreads();
        if (tid == 0) partials[bid] = ws[0] + ws[1] + ws[2] + ws[3];
    }
    grid.sync();

    // P3: block 0 exclusive-scans the 196 partials
    if (bid == 0) {
        int v = (tid < SCAN_BLOCKS) ? partials[tid] : 0;
        int x = v;
        #pragma unroll
        for (int d = 1; d < 64; d <<= 1) {
            int y = __shfl_up(x, d);
            if (lane >= d) x += y;
        }
        if (lane == 63) ws[wid] = x;
        __syncthreads();
        int woff = 0;
        for (int w = 0; w < wid; ++w) woff += ws[w];
        if (tid < SCAN_BLOCKS) partials[tid] = woff + x - v;   // exclusive
        if (tid == 255) offsets[N_NODES] = woff + x;           // grand total
    }
    grid.sync();

    // P4: block-local exclusive scan + partial offset -> offsets, cursor
    if (bid < SCAN_BLOCKS) {
        int i = bid * 256 + tid;
        int v = (i < N_NODES) ? cnt[i] : 0;
        int x = v;
        #pragma unroll
        for (int d = 1; d < 64; d <<= 1) {
            int y = __shfl_up(x, d);
            if (lane >= d) x += y;
        }
        if (lane == 63) ws[wid] = x;
        __syncthreads();
        int woff = 0;
        for (int w = 0; w < wid; ++w) woff += ws[w];
        if (i < N_NODES) {
            int off = partials[bid] + woff + x - v;
            offsets[i] = off;
            cursor[i] = off;
        }
    }
    grid.sync();

    // P5: bucketize sources per destination
    for (int e = gid; e < N_EDGES; e += gstride) {
        int c = col[e];
        int p = atomicAdd(&cursor[c], 1);
        srcbuf[p] = row[e];
    }
}

// ---------------- GEMM via split-bf16 MFMA (round-8/10 verified structure) ----------------
template <bool BN>
__global__ __launch_bounds__(256) void gemm_mfma(const float* __restrict__ A,
                                                 const ushort_t* __restrict__ wt,
                                                 const float* __restrict__ stats,
                                                 const float* __restrict__ gamma,
                                                 const float* __restrict__ beta,
                                                 ushort_t* __restrict__ C) {
    __shared__ short lds[32768];  // Ah[0,8192) Al[8192,16384) Wh[16384,24576) Wl[24576,32768)
    __shared__ float cs[256];     // scale[0:128], shift[128:256]
    int tid = threadIdx.x;
    long r0 = (long)blockIdx.x * 64;
    const float4* A4 = (const float4*)A;

    if (BN) {
        if (tid < 128) {
            float inv = 1.0f / (float)NROWS;
            float mean = stats[tid] * inv;
            float var = stats[128 + tid] * inv - mean * mean;
            float scale = gamma[tid] / sqrtf(var + BN_EPS);
            cs[tid] = scale;
            cs[128 + tid] = beta[tid] - mean * scale;
        }
        __syncthreads();
    }
    const float4* coef4 = (const float4*)cs;

    #pragma unroll
    for (int i = 0; i < 4; ++i) {
        int li = tid + i * 256;
        int r = li >> 4, j = li & 15;        // row 0..63, k-block 0..15
        long gr = r0 + r;
        float4 va = make_float4(0.f, 0.f, 0.f, 0.f), vb = va;
        if (gr < NROWS) { va = A4[gr * 32 + j * 2]; vb = A4[gr * 32 + j * 2 + 1]; }
        if (BN) {
            float4 sc = coef4[j * 2], sh = coef4[32 + j * 2];
            va.x = fmaxf(va.x * sc.x + sh.x, 0.f);
            va.y = fmaxf(va.y * sc.y + sh.y, 0.f);
            va.z = fmaxf(va.z * sc.z + sh.z, 0.f);
            va.w = fmaxf(va.w * sc.w + sh.w, 0.f);
            sc = coef4[j * 2 + 1]; sh = coef4[32 + j * 2 + 1];
            vb.x = fmaxf(vb.x * sc.x + sh.x, 0.f);
            vb.y = fmaxf(vb.y * sc.y + sh.y, 0.f);
            vb.z = fmaxf(vb.z * sc.z + sh.z, 0.f);
            vb.w = fmaxf(vb.w * sc.w + sh.w, 0.f);
        }
        bf16x8 vh, vl;
        split4(va, vh, vl, 0);
        split4(vb, vh, vl, 4);
        int off = r * 128 + ((j ^ (r & 15)) * 8);
        *(bf16x8*)&lds[off] = vh;
        *(bf16x8*)&lds[8192 + off] = vl;
    }

    int w = tid >> 6, l = tid & 63;
    int m = l & 15, q = l >> 4;
    for (int half = 0; half < 2; ++half) {
        __syncthreads();
        #pragma unroll
        for (int i = 0; i < 8; ++i) {
            int li = tid + i * 256;
            int p = li >> 10;                 // 0=hi 1=lo
            int rest = li & 1023;
            int nl = rest >> 4, j = rest & 15;
            bf16x8 v = *(const bf16x8*)&wt[(size_t)p * 16384 + (half * 64 + nl) * 128 + j * 8];
            *(bf16x8*)&lds[16384 + p * 8192 + nl * 128 + ((j ^ (nl & 15)) * 8)] = v;
        }
        __syncthreads();

        f32x4 acc[4] = {};
        #pragma unroll
        for (int s = 0; s < 4; ++s) {
            int x = (s * 4 + q) ^ m;
            int aoff = (w * 16 + m) * 128 + x * 8;
            bf16x8 ah = *(const bf16x8*)&lds[aoff];
            bf16x8 al = *(const bf16x8*)&lds[8192 + aoff];
            #pragma unroll
            for (int c = 0; c < 4; ++c) {
                int boff = 16384 + (c * 16 + m) * 128 + x * 8;
                bf16x8 bh = *(const bf16x8*)&lds[boff];
                bf16x8 bl = *(const bf16x8*)&lds[8192 + boff];
                acc[c] = __builtin_amdgcn_mfma_f32_16x16x32_bf16(al, bh, acc[c], 0, 0, 0);
                acc[c] = __builtin_amdgcn_mfma_f32_16x16x32_bf16(ah, bl, acc[c], 0, 0, 0);
                acc[c] = __builtin_amdgcn_mfma_f32_16x16x32_bf16(ah, bh, acc[c], 0, 0, 0);
            }
        }

        // write C (bf16, interleaved rows): row gr -> (node*2 + b)*128
        #pragma unroll
        for (int c = 0; c < 4; ++c) {
            #pragma unroll
            for (int r = 0; r < 4; ++r) {
                long gr = r0 + w * 16 + q * 4 + r;
                if (gr < NROWS) {
                    int b = gr >= N_NODES;
                    long node = gr - (long)b * N_NODES;
                    C[(node * 2 + b) * 128 + half * 64 + c * 16 + m] = f2bf(acc[c][r]);
                }
            }
        }
    }
}

// ---------------- Cooperative aggregate (verified hot loop) + BN stats ----------------
__global__ __launch_bounds__(256, 8) void agg_stats_coop(const ushort_t* __restrict__ sup,
                                                         const int* __restrict__ offsets,
                                                         const int* __restrict__ srcbuf,
                                                         float* __restrict__ agg,
                                                         float* __restrict__ stats) {
    cg::grid_group grid = cg::this_grid();
    int tid = threadIdx.x;
    int lane = tid & 63;
    int wid = tid >> 6;
    int s = lane >> 5;       // half-wave id
    int l32 = lane & 31;
    const ushort4* sb = (const ushort4*)sup;   // row r: [r*64, +32)=batch0, [+32, +64)=batch1
    float4* ag = (float4*)agg;

    for (int nb = blockIdx.x; nb < 12500; nb += gridDim.x) {
        int node = nb * 4 + wid;             // covers 0..49999 exactly
        int beg = offsets[node], end = offsets[node + 1];
        float4 a0 = make_float4(0.f, 0.f, 0.f, 0.f);
        float4 a1 = make_float4(0.f, 0.f, 0.f, 0.f);
        for (int i = beg; i < end; i += 64) {
            int m = end - i; if (m > 64) m = 64;
            int idx = (i + lane < end) ? srcbuf[i + lane] : 0;  // coalesced index load
            int tmax = (m + 1) >> 1;
            #pragma unroll 2
            for (int t = 0; t < tmax; ++t) {
                int j = 2 * t + s;
                int r = __shfl(idx, j & 63);
                ushort4 u0 = sb[(size_t)r * 64 + l32];        // batch 0 half-row
                ushort4 u1 = sb[(size_t)r * 64 + 32 + l32];   // batch 1 half-row
                if (j < m) {
                    float4 f0 = bf4_to_f4(u0);
                    float4 f1 = bf4_to_f4(u1);
                    a0.x += f0.x; a0.y += f0.y; a0.z += f0.z; a0.w += f0.w;
                    a1.x += f1.x; a1.y += f1.y; a1.z += f1.z; a1.w += f1.w;
                }
            }
        }
        a0.x += __shfl_xor(a0.x, 32); a0.y += __shfl_xor(a0.y, 32);
        a0.z += __shfl_xor(a0.z, 32); a0.w += __shfl_xor(a0.w, 32);
        a1.x += __shfl_xor(a1.x, 32); a1.y += __shfl_xor(a1.y, 32);
        a1.z += __shfl_xor(a1.z, 32); a1.w += __shfl_xor(a1.w, 32);
        if (s == 0) ag[(size_t)node * 32 + l32] = a0;                   // batch 0 row
        else        ag[(size_t)(N_NODES + node) * 32 + l32] = a1;       // batch 1 row
    }
    grid.sync();

    // BN stats phase: exact bn_stats body on virtual 512 blocks (others done)
    if (blockIdx.x >= 512) return;
    __shared__ float ls[256], ls2[256];
    int f = tid & 127, half = tid >> 7;
    float sm = 0.f, s2 = 0.f;
    const float* h = agg;
    for (int r = blockIdx.x * 2 + half; r < NROWS; r += 1024) {
        float v = h[(size_t)r * FDIM + f];
        sm += v; s2 += v * v;
    }
    ls[tid] = sm; ls2[tid] = s2;
    __syncthreads();
    if (tid < 128) {
        atomicAdd(&stats[f], ls[tid] + ls[tid + 128]);
        atomicAdd(&stats[128 + f], ls2[tid] + ls2[tid + 128]);
    }
}

// ---------------- Cooperative layer 3: BN+ReLU GEMV + CSR gather ----------------
__global__ __launch_bounds__(256, 4) void gemv_gather_coop(const float* __restrict__ h,
                                                           const float* __restrict__ stats,
                                                           const float* __restrict__ gamma,
                                                           const float* __restrict__ beta,
                                                           const float* __restrict__ W3,
                                                           const float* __restrict__ b3,
                                                           const int* __restrict__ offsets,
                                                           const int* __restrict__ srcbuf,
                                                           float* __restrict__ sup3,
                                                           float* __restrict__ out) {
    cg::grid_group grid = cg::this_grid();
    __shared__ float cs[256];
    int tid = threadIdx.x;
    if (tid < 128) {
        float inv = 1.0f / (float)NROWS;
        float mean = stats[tid] * inv;
        float var = stats[128 + tid] * inv - mean * mean;
        float scale = gamma[tid] / sqrtf(var + BN_EPS);
        cs[tid] = scale;
        cs[128 + tid] = beta[tid] - mean * scale;
    }
    __syncthreads();
    int lane = tid & 63, wid = tid >> 6;
    float2 w  = ((const float2*)W3)[lane];
    float2 sc = ((const float2*)cs)[lane];
    float2 sh = ((const float2*)(cs + 128))[lane];
    for (int vb = blockIdx.x; vb < 6250; vb += gridDim.x) {
        #pragma unroll
        for (int r = 0; r < 4; ++r) {
            long gw = (long)vb * 16 + wid * 4 + r;   // 6250*16 = 100000 exactly
            float2 v = ((const float2*)h)[(size_t)gw * 64 + lane];
            v.x = fmaxf(v.x * sc.x + sh.x, 0.f);
            v.y = fmaxf(v.y * sc.y + sh.y, 0.f);
            float s = v.x * w.x + v.y * w.y;
            #pragma unroll
            for (int d = 32; d > 0; d >>= 1) s += __shfl_xor(s, d);
            if (lane == 0) sup3[gw] = s;
        }
    }
    grid.sync();

    // gather phase: out[b,n] = b3 + sum over CSR in-edges of sup3[b, src]
    if (blockIdx.x >= SCAN_BLOCKS) return;
    int n = blockIdx.x * 256 + tid;
    if (n >= N_NODES) return;
    int beg = offsets[n], end = offsets[n + 1];
    float s0 = 0.f, s1 = 0.f;
    for (int i = beg; i < end; ++i) {
        int r = srcbuf[i];
        s0 += sup3[r];
        s1 += sup3[N_NODES + r];
    }
    float b = b3[0];
    out[n] = s0 + b;
    out[N_NODES + n] = s1 + b;
}

// ---------------- launch ----------------

extern "C" void kernel_launch(void* const* d_in, const int* in_sizes, int n_in,
                              void* d_out, int out_size, void* d_ws, size_t ws_size,
                              hipStream_t stream) {
    const float* x      = (const float*)d_in[0];
    const int*   ei     = (const int*)d_in[1];
    const float* W1     = (const float*)d_in[2];
    // d_in[3] = b1: per-feature bias before BN cancels exactly (shifts mean identically)
    const float* W2     = (const float*)d_in[4];
    // d_in[5] = b2: same cancellation
    const float* W3     = (const float*)d_in[6];
    const float* b3     = (const float*)d_in[7];
    const float* gamma1 = (const float*)d_in[8];
    const float* beta1  = (const float*)d_in[9];
    const float* gamma2 = (const float*)d_in[10];
    const float* beta2  = (const float*)d_in[11];
    const int* rowp = ei;             // edge_index[0]
    const int* colp = ei + N_EDGES;   // edge_index[1]

    ushort_t* sup   = (ushort_t*)d_ws;              // 12.8M bf16 (25.6 MB), [node][batch][128]
    float* agg      = (float*)(sup + 12800000);     // 12.8M floats (51.2 MB), [b*N+node][128]
    float* sup3     = agg + 12800000;               // 100k floats
    ushort_t* wt    = (ushort_t*)(sup3 + 100000);   // 65536 ushorts: W1/W2 split planes
    float* stats    = (float*)(wt + 65536);         // 512 floats
    int*   cnt      = (int*)(stats + 512);          // 50000
    int*   offsets  = cnt + N_NODES;                // 50001
    int*   cursor   = offsets + N_NODES + 1;        // 50000
    int*   srcbuf   = cursor + N_NODES;             // 800000
    int*   scanp    = srcbuf + N_EDGES;             // 196
    float* out      = (float*)d_out;

    float* stats2 = stats + 256;
    ushort_t* wt2 = wt + 32768;

    // occupancy-clamped cooperative grids (host-side queries only; capture-safe)
    int nb_csr = 4, nb_agg = 8, nb_gg = 4;
    hipOccupancyMaxActiveBlocksPerMultiprocessor(&nb_csr, csr_build_coop, 256, 0);
    hipOccupancyMaxActiveBlocksPerMultiprocessor(&nb_agg, agg_stats_coop, 256, 0);
    hipOccupancyMaxActiveBlocksPerMultiprocessor(&nb_gg, gemv_gather_coop, 256, 0);
    int g_csr = min(1024, nb_csr * 256); if (g_csr < 256) g_csr = 256;
    int g_agg = min(2048, nb_agg * 256); if (g_agg < 512) g_agg = 512;
    int g_gg  = min(1024, nb_gg * 256);  if (g_gg < 256) g_gg = 256;

    // 1. CSR build (+ W split + zeroing) — one cooperative dispatch
    {
        void* args[] = {(void*)&W1, (void*)&W2, (void*)&rowp, (void*)&colp,
                        (void*)&wt, (void*)&cnt, (void*)&stats, (void*)&offsets,
                        (void*)&cursor, (void*)&scanp, (void*)&srcbuf};
        hipLaunchCooperativeKernel(csr_build_coop, dim3(g_csr), dim3(256), args, 0, stream);
    }

    // 2. layer 1 GEMM: sup = x@W1 (split-bf16 MFMA, interleaved C)
    gemm_mfma<false><<<1563, 256, 0, stream>>>(x, wt, nullptr, nullptr, nullptr, sup);

    // 3. layer 1 aggregate + BN1 stats — one cooperative dispatch
    {
        void* args[] = {(void*)&sup, (void*)&offsets, (void*)&srcbuf,
                        (void*)&agg, (void*)&stats};
        hipLaunchCooperativeKernel(agg_stats_coop, dim3(g_agg), dim3(256), args, 0, stream);
    }

    // 4. layer 2 GEMM: sup = relu(bn1(agg))@W2 (coef in-block)
    gemm_mfma<true><<<1563, 256, 0, stream>>>(agg, wt2, stats, gamma1, beta1, sup);

    // 5. layer 2 aggregate + BN2 stats
    {
        void* args[] = {(void*)&sup, (void*)&offsets, (void*)&srcbuf,
                        (void*)&agg, (void*)&stats2};
        hipLaunchCooperativeKernel(agg_stats_coop, dim3(g_agg), dim3(256), args, 0, stream);
    }

    // 6. layer 3: gemv (bn2 fused) + output gather — one cooperative dispatch
    {
        void* args[] = {(void*)&agg, (void*)&stats2, (void*)&gamma2, (void*)&beta2,
                        (void*)&W3, (void*)&b3, (void*)&offsets, (void*)&srcbuf,
                        (void*)&sup3, (void*)&out};
        hipLaunchCooperativeKernel(gemv_gather_coop, dim3(g_gg), dim3(256), args, 0, stream);
    }
}

// Round 12
// 477.880 us; speedup vs baseline: 2.9785x; 2.9785x over previous
//
#include <hip/hip_runtime.h>

#define N_NODES 50000
#define N_EDGES 800000
#define FDIM 128
#define NROWS 100000   // B * N_NODES
#define BN_EPS 1e-5f
#define SCAN_BLOCKS 196   // ceil(50000 / 256)

typedef unsigned short ushort_t;
typedef unsigned int uint_t;
typedef __attribute__((ext_vector_type(8))) short bf16x8;   // MFMA A/B frag
typedef __attribute__((ext_vector_type(4))) float f32x4;    // MFMA C/D frag

// round-to-nearest-even fp32 -> bf16
__device__ inline ushort_t f2bf(float f) {
    uint_t x = __float_as_uint(f);
    x += 0x7fffu + ((x >> 16) & 1u);
    return (ushort_t)(x >> 16);
}
__device__ inline float4 bf4_to_f4(ushort4 u) {
    float4 f;
    f.x = __uint_as_float((uint_t)u.x << 16);
    f.y = __uint_as_float((uint_t)u.y << 16);
    f.z = __uint_as_float((uint_t)u.z << 16);
    f.w = __uint_as_float((uint_t)u.w << 16);
    return f;
}
// split-bf16: f = hi + lo with |err| ~ 2^-18 |f|
__device__ inline void split4(float4 v, bf16x8& hi, bf16x8& lo, int base) {
    float f[4] = {v.x, v.y, v.z, v.w};
    #pragma unroll
    for (int t = 0; t < 4; ++t) {
        ushort_t h = f2bf(f[t]);
        float fh = __uint_as_float((uint_t)h << 16);
        ushort_t l = f2bf(f[t] - fh);
        hi[base + t] = (short)h;
        lo[base + t] = (short)l;
    }
}

// ---------------- CSR build (per-destination buckets) ----------------

__global__ __launch_bounds__(256) void hist_kernel(const int* __restrict__ col,
                                                   int* __restrict__ cnt) {
    int e = blockIdx.x * 256 + threadIdx.x;
    if (e < N_EDGES) atomicAdd(&cnt[col[e]], 1);
}

// Single-dispatch scan (no grid sync): block bid re-reduces cnt[0..bid*256) for its
// base prefix (L2-hot, <=50k ints), then block-local exclusive scan -> offsets/cursor.
__global__ __launch_bounds__(256) void scan_all(const int* __restrict__ cnt,
                                                int* __restrict__ offsets,
                                                int* __restrict__ cursor) {
    __shared__ int ws[4];
    int tid = threadIdx.x, bid = blockIdx.x;
    int lane = tid & 63, wid = tid >> 6;

    // base = sum of cnt[0 .. bid*256)
    int s = 0;
    for (int i = tid; i < bid * 256; i += 256) s += cnt[i];
    #pragma unroll
    for (int d = 32; d > 0; d >>= 1) s += __shfl_xor(s, d);
    if (lane == 0) ws[wid] = s;
    __syncthreads();
    int base = ws[0] + ws[1] + ws[2] + ws[3];
    __syncthreads();   // ws reused below

    // block-local exclusive scan
    int i = bid * 256 + tid;
    int v = (i < N_NODES) ? cnt[i] : 0;
    int x = v;
    #pragma unroll
    for (int d = 1; d < 64; d <<= 1) {
        int y = __shfl_up(x, d);
        if (lane >= d) x += y;
    }
    if (lane == 63) ws[wid] = x;
    __syncthreads();
    int woff = 0;
    for (int w = 0; w < wid; ++w) woff += ws[w];
    if (i < N_NODES) {
        int off = base + woff + x - v;
        offsets[i] = off;
        cursor[i] = off;
    }
    if (bid == SCAN_BLOCKS - 1 && tid == 255)
        offsets[N_NODES] = base + woff + x;   // grand total
}

__global__ __launch_bounds__(256) void bucket_kernel(const int* __restrict__ row,
                                                     const int* __restrict__ col,
                                                     int* __restrict__ cursor,
                                                     int* __restrict__ srcbuf) {
    int e = blockIdx.x * 256 + threadIdx.x;
    if (e < N_EDGES) {
        int c = col[e];
        int p = atomicAdd(&cursor[c], 1);
        srcbuf[p] = row[e];
    }
}

// ---------------- W pre-transform + workspace zeroing ----------------
__global__ __launch_bounds__(256) void wsplit_kernel(const float* __restrict__ W1,
                                                     const float* __restrict__ W2,
                                                     ushort_t* __restrict__ wt,
                                                     int* __restrict__ cnt,
                                                     float* __restrict__ stats) {
    int idx = blockIdx.x * 256 + threadIdx.x;   // 0..32767
    for (int i = idx; i < N_NODES; i += 32768) cnt[i] = 0;
    if (idx < 512) stats[idx] = 0.f;
    int which = idx >> 14;
    int e = idx & 16383;                         // e = k*128 + n (coalesced read)
    int k = e >> 7, n = e & 127;
    float f = (which ? W2 : W1)[e];
    ushort_t h = f2bf(f);
    float fh = __uint_as_float((uint_t)h << 16);
    ushort_t l = f2bf(f - fh);
    size_t base = (size_t)which * 32768;
    wt[base + n * 128 + k] = h;                  // hi plane
    wt[base + 16384 + n * 128 + k] = l;          // lo plane
}

// ---------------- GEMM via split-bf16 MFMA (round-8/10 verified structure) ----------------
// W staged to LDS per 64-col half; BN coef computed in-block; C written to the
// interleaved sup layout [node][batch][128] bf16 (512B/node for the gather).
template <bool BN>
__global__ __launch_bounds__(256) void gemm_mfma(const float* __restrict__ A,
                                                 const ushort_t* __restrict__ wt,
                                                 const float* __restrict__ stats,
                                                 const float* __restrict__ gamma,
                                                 const float* __restrict__ beta,
                                                 ushort_t* __restrict__ C) {
    __shared__ short lds[32768];  // Ah[0,8192) Al[8192,16384) Wh[16384,24576) Wl[24576,32768)
    __shared__ float cs[256];     // scale[0:128], shift[128:256]
    int tid = threadIdx.x;
    long r0 = (long)blockIdx.x * 64;
    const float4* A4 = (const float4*)A;

    if (BN) {
        if (tid < 128) {
            float inv = 1.0f / (float)NROWS;
            float mean = stats[tid] * inv;
            float var = stats[128 + tid] * inv - mean * mean;
            float scale = gamma[tid] / sqrtf(var + BN_EPS);
            cs[tid] = scale;
            cs[128 + tid] = beta[tid] - mean * scale;
        }
        __syncthreads();
    }
    const float4* coef4 = (const float4*)cs;

    #pragma unroll
    for (int i = 0; i < 4; ++i) {
        int li = tid + i * 256;
        int r = li >> 4, j = li & 15;        // row 0..63, k-block 0..15
        long gr = r0 + r;
        float4 va = make_float4(0.f, 0.f, 0.f, 0.f), vb = va;
        if (gr < NROWS) { va = A4[gr * 32 + j * 2]; vb = A4[gr * 32 + j * 2 + 1]; }
        if (BN) {
            float4 sc = coef4[j * 2], sh = coef4[32 + j * 2];
            va.x = fmaxf(va.x * sc.x + sh.x, 0.f);
            va.y = fmaxf(va.y * sc.y + sh.y, 0.f);
            va.z = fmaxf(va.z * sc.z + sh.z, 0.f);
            va.w = fmaxf(va.w * sc.w + sh.w, 0.f);
            sc = coef4[j * 2 + 1]; sh = coef4[32 + j * 2 + 1];
            vb.x = fmaxf(vb.x * sc.x + sh.x, 0.f);
            vb.y = fmaxf(vb.y * sc.y + sh.y, 0.f);
            vb.z = fmaxf(vb.z * sc.z + sh.z, 0.f);
            vb.w = fmaxf(vb.w * sc.w + sh.w, 0.f);
        }
        bf16x8 vh, vl;
        split4(va, vh, vl, 0);
        split4(vb, vh, vl, 4);
        int off = r * 128 + ((j ^ (r & 15)) * 8);
        *(bf16x8*)&lds[off] = vh;
        *(bf16x8*)&lds[8192 + off] = vl;
    }

    int w = tid >> 6, l = tid & 63;
    int m = l & 15, q = l >> 4;
    for (int half = 0; half < 2; ++half) {
        __syncthreads();
        #pragma unroll
        for (int i = 0; i < 8; ++i) {
            int li = tid + i * 256;
            int p = li >> 10;                 // 0=hi 1=lo
            int rest = li & 1023;
            int nl = rest >> 4, j = rest & 15;
            bf16x8 v = *(const bf16x8*)&wt[(size_t)p * 16384 + (half * 64 + nl) * 128 + j * 8];
            *(bf16x8*)&lds[16384 + p * 8192 + nl * 128 + ((j ^ (nl & 15)) * 8)] = v;
        }
        __syncthreads();

        f32x4 acc[4] = {};
        #pragma unroll
        for (int s = 0; s < 4; ++s) {
            int x = (s * 4 + q) ^ m;
            int aoff = (w * 16 + m) * 128 + x * 8;
            bf16x8 ah = *(const bf16x8*)&lds[aoff];
            bf16x8 al = *(const bf16x8*)&lds[8192 + aoff];
            #pragma unroll
            for (int c = 0; c < 4; ++c) {
                int boff = 16384 + (c * 16 + m) * 128 + x * 8;
                bf16x8 bh = *(const bf16x8*)&lds[boff];
                bf16x8 bl = *(const bf16x8*)&lds[8192 + boff];
                acc[c] = __builtin_amdgcn_mfma_f32_16x16x32_bf16(al, bh, acc[c], 0, 0, 0);
                acc[c] = __builtin_amdgcn_mfma_f32_16x16x32_bf16(ah, bl, acc[c], 0, 0, 0);
                acc[c] = __builtin_amdgcn_mfma_f32_16x16x32_bf16(ah, bh, acc[c], 0, 0, 0);
            }
        }

        // write C (bf16, interleaved rows): row gr -> (node*2 + b)*128
        #pragma unroll
        for (int c = 0; c < 4; ++c) {
            #pragma unroll
            for (int r = 0; r < 4; ++r) {
                long gr = r0 + w * 16 + q * 4 + r;
                if (gr < NROWS) {
                    int b = gr >= N_NODES;
                    long node = gr - (long)b * N_NODES;
                    C[(node * 2 + b) * 128 + half * 64 + c * 16 + m] = f2bf(acc[c][r]);
                }
            }
        }
    }
}

// ---------------- Aggregate (verified hot loop; interleaved sup rows; unroll 4) ----------------
__global__ __launch_bounds__(256) void aggregate_bf16(const ushort_t* __restrict__ sup,
                                                      const int* __restrict__ offsets,
                                                      const int* __restrict__ srcbuf,
                                                      float* __restrict__ agg) {
    int lane = threadIdx.x & 63;
    int wid = threadIdx.x >> 6;
    int node = blockIdx.x * 4 + wid;        // 12500*4 = 50000 exactly
    int s = lane >> 5;       // half-wave id
    int l32 = lane & 31;
    int beg = offsets[node], end = offsets[node + 1];
    const ushort4* sb = (const ushort4*)sup;   // row r: [r*64, r*64+32)=batch0, +32..64)=batch1
    float4 a0 = make_float4(0.f, 0.f, 0.f, 0.f);
    float4 a1 = make_float4(0.f, 0.f, 0.f, 0.f);
    for (int i = beg; i < end; i += 64) {
        int m = end - i; if (m > 64) m = 64;
        int idx = (i + lane < end) ? srcbuf[i + lane] : 0;  // coalesced index load
        int tmax = (m + 1) >> 1;
        #pragma unroll 4
        for (int t = 0; t < tmax; ++t) {
            int j = 2 * t + s;
            int r = __shfl(idx, j & 63);
            ushort4 u0 = sb[(size_t)r * 64 + l32];        // batch 0 half-row
            ushort4 u1 = sb[(size_t)r * 64 + 32 + l32];   // batch 1 half-row
            if (j < m) {
                float4 f0 = bf4_to_f4(u0);
                float4 f1 = bf4_to_f4(u1);
                a0.x += f0.x; a0.y += f0.y; a0.z += f0.z; a0.w += f0.w;
                a1.x += f1.x; a1.y += f1.y; a1.z += f1.z; a1.w += f1.w;
            }
        }
    }
    a0.x += __shfl_xor(a0.x, 32); a0.y += __shfl_xor(a0.y, 32);
    a0.z += __shfl_xor(a0.z, 32); a0.w += __shfl_xor(a0.w, 32);
    a1.x += __shfl_xor(a1.x, 32); a1.y += __shfl_xor(a1.y, 32);
    a1.z += __shfl_xor(a1.z, 32); a1.w += __shfl_xor(a1.w, 32);
    float4* ag = (float4*)agg;
    if (s == 0) ag[(size_t)node * 32 + l32] = a0;                       // batch 0 row
    else        ag[(size_t)(N_NODES + node) * 32 + l32] = a1;           // batch 1 row
}

// ---------------- BatchNorm stats (over raw agg) ----------------

__global__ __launch_bounds__(256) void bn_stats_kernel(const float* __restrict__ h,
                                                       float* __restrict__ stats) {
    __shared__ float ls[256], ls2[256];
    int tid = threadIdx.x;
    int f = tid & 127, half = tid >> 7;
    float s = 0.f, s2 = 0.f;
    for (int row = blockIdx.x * 2 + half; row < NROWS; row += gridDim.x * 2) {
        float v = h[(size_t)row * FDIM + f];
        s += v; s2 += v * v;
    }
    ls[tid] = s; ls2[tid] = s2;
    __syncthreads();
    if (tid < 128) {
        atomicAdd(&stats[f], ls[tid] + ls[tid + 128]);
        atomicAdd(&stats[128 + f], ls2[tid] + ls2[tid + 128]);
    }
}

// ---------------- Layer 3: fused BN+ReLU GEMV (coef in-block) + CSR gather ----------------
__global__ __launch_bounds__(256) void gemv_bn_kernel(const float* __restrict__ h,
                                                      const float* __restrict__ stats,
                                                      const float* __restrict__ gamma,
                                                      const float* __restrict__ beta,
                                                      const float* __restrict__ W3,
                                                      float* __restrict__ sup3) {
    __shared__ float cs[256];
    int tid = threadIdx.x;
    if (tid < 128) {
        float inv = 1.0f / (float)NROWS;
        float mean = stats[tid] * inv;
        float var = stats[128 + tid] * inv - mean * mean;
        float scale = gamma[tid] / sqrtf(var + BN_EPS);
        cs[tid] = scale;
        cs[128 + tid] = beta[tid] - mean * scale;
    }
    __syncthreads();
    int lane = tid & 63, wid = tid >> 6;
    float2 w  = ((const float2*)W3)[lane];
    float2 sc = ((const float2*)cs)[lane];
    float2 sh = ((const float2*)(cs + 128))[lane];
    #pragma unroll
    for (int r = 0; r < 4; ++r) {
        long gw = (long)blockIdx.x * 16 + wid * 4 + r;   // 6250*16 = 100000 exactly
        float2 v = ((const float2*)h)[(size_t)gw * 64 + lane];
        v.x = fmaxf(v.x * sc.x + sh.x, 0.f);
        v.y = fmaxf(v.y * sc.y + sh.y, 0.f);
        float s = v.x * w.x + v.y * w.y;
        #pragma unroll
        for (int d = 32; d > 0; d >>= 1) s += __shfl_xor(s, d);
        if (lane == 0) sup3[gw] = s;
    }
}

// out[b,n] = b3 + sum over CSR in-edges of sup3[b, src].
__global__ __launch_bounds__(256) void gather_out_kernel(const int* __restrict__ offsets,
                                                         const int* __restrict__ srcbuf,
                                                         const float* __restrict__ sup3,
                                                         const float* __restrict__ b3,
                                                         float* __restrict__ out) {
    int n = blockIdx.x * 256 + threadIdx.x;
    if (n >= N_NODES) return;
    int beg = offsets[n], end = offsets[n + 1];
    float s0 = 0.f, s1 = 0.f;
    for (int i = beg; i < end; ++i) {
        int r = srcbuf[i];
        s0 += sup3[r];
        s1 += sup3[N_NODES + r];
    }
    float b = b3[0];
    out[n] = s0 + b;
    out[N_NODES + n] = s1 + b;
}

// ---------------- launch ----------------

extern "C" void kernel_launch(void* const* d_in, const int* in_sizes, int n_in,
                              void* d_out, int out_size, void* d_ws, size_t ws_size,
                              hipStream_t stream) {
    const float* x      = (const float*)d_in[0];
    const int*   ei     = (const int*)d_in[1];
    const float* W1     = (const float*)d_in[2];
    // d_in[3] = b1: per-feature bias before BN cancels exactly (shifts mean identically)
    const float* W2     = (const float*)d_in[4];
    // d_in[5] = b2: same cancellation
    const float* W3     = (const float*)d_in[6];
    const float* b3     = (const float*)d_in[7];
    const float* gamma1 = (const float*)d_in[8];
    const float* beta1  = (const float*)d_in[9];
    const float* gamma2 = (const float*)d_in[10];
    const float* beta2  = (const float*)d_in[11];
    const int* rowp = ei;             // edge_index[0]
    const int* colp = ei + N_EDGES;   // edge_index[1]

    ushort_t* sup   = (ushort_t*)d_ws;              // 12.8M bf16 (25.6 MB), [node][batch][128]
    float* agg      = (float*)(sup + 12800000);     // 12.8M floats (51.2 MB), [b*N+node][128]
    float* sup3     = agg + 12800000;               // 100k floats
    ushort_t* wt    = (ushort_t*)(sup3 + 100000);   // 65536 ushorts: W1/W2 split planes
    float* stats    = (float*)(wt + 65536);         // 512 floats
    int*   cnt      = (int*)(stats + 512);          // 50000
    int*   offsets  = cnt + N_NODES;                // 50001
    int*   cursor   = offsets + N_NODES + 1;        // 50000
    int*   srcbuf   = cursor + N_NODES;             // 800000
    float* out      = (float*)d_out;

    // W split/transpose + cnt/stats zeroing, then CSR build (hist -> scan -> bucket)
    wsplit_kernel<<<128,         256, 0, stream>>>(W1, W2, wt, cnt, stats);
    hist_kernel  <<<3125,        256, 0, stream>>>(colp, cnt);
    scan_all     <<<SCAN_BLOCKS, 256, 0, stream>>>(cnt, offsets, cursor);
    bucket_kernel<<<3125,        256, 0, stream>>>(rowp, colp, cursor, srcbuf);

    // layer 1: sup = x@W1 (split-bf16 MFMA, interleaved C), agg = A·sup, stats
    gemm_mfma<false><<<1563,  256, 0, stream>>>(x, wt, nullptr, nullptr, nullptr, sup);
    aggregate_bf16  <<<12500, 256, 0, stream>>>(sup, offsets, srcbuf, agg);
    bn_stats_kernel <<<512,   256, 0, stream>>>(agg, stats);

    // layer 2: sup = relu(bn1(agg))@W2 (coef computed in-block), agg = A·sup, stats
    gemm_mfma<true> <<<1563,  256, 0, stream>>>(agg, wt + 32768, stats, gamma1, beta1, sup);
    aggregate_bf16  <<<12500, 256, 0, stream>>>(sup, offsets, srcbuf, agg);
    bn_stats_kernel <<<512,   256, 0, stream>>>(agg, stats + 256);

    // layer 3: sup3 = relu(bn2(agg))@W3 (coef in-block), out = A·sup3 + b3 (CSR gather)
    gemv_bn_kernel   <<<6250, 256, 0, stream>>>(agg, stats + 256, gamma2, beta2, W3, sup3);
    gather_out_kernel<<<SCAN_BLOCKS, 256, 0, stream>>>(offsets, srcbuf, sup3, b3, out);
}

// Round 13
// 449.528 us; speedup vs baseline: 3.1664x; 1.0631x over previous
//
#include <hip/hip_runtime.h>

#define N_NODES 50000
#define N_EDGES 800000
#define FDIM 128
#define NROWS 100000   // B * N_NODES
#define BN_EPS 1e-5f
#define SCAN_BLOCKS 196   // ceil(50000 / 256)

typedef unsigned short ushort_t;
typedef unsigned int uint_t;
typedef __attribute__((ext_vector_type(8))) short bf16x8;   // MFMA A/B frag
typedef __attribute__((ext_vector_type(4))) float f32x4;    // MFMA C/D frag

// round-to-nearest-even fp32 -> bf16
__device__ inline ushort_t f2bf(float f) {
    uint_t x = __float_as_uint(f);
    x += 0x7fffu + ((x >> 16) & 1u);
    return (ushort_t)(x >> 16);
}
__device__ inline float4 bf4_to_f4(ushort4 u) {
    float4 f;
    f.x = __uint_as_float((uint_t)u.x << 16);
    f.y = __uint_as_float((uint_t)u.y << 16);
    f.z = __uint_as_float((uint_t)u.z << 16);
    f.w = __uint_as_float((uint_t)u.w << 16);
    return f;
}
// bf16 round of 4 floats into an 8-wide frag at base
__device__ inline void round4(float4 v, bf16x8& hi, int base) {
    hi[base + 0] = (short)f2bf(v.x);
    hi[base + 1] = (short)f2bf(v.y);
    hi[base + 2] = (short)f2bf(v.z);
    hi[base + 3] = (short)f2bf(v.w);
}

// ---------------- CSR build (per-destination buckets) ----------------

__global__ __launch_bounds__(256) void hist_kernel(const int* __restrict__ col,
                                                   int* __restrict__ cnt) {
    int e = blockIdx.x * 256 + threadIdx.x;
    if (e < N_EDGES) atomicAdd(&cnt[col[e]], 1);
}

__global__ __launch_bounds__(256) void scan_partials_sum(const int* __restrict__ cnt,
                                                         int* __restrict__ partials) {
    __shared__ int ws[4];
    int tid = threadIdx.x, lane = tid & 63, wid = tid >> 6;
    int i = blockIdx.x * 256 + tid;
    int v = (i < N_NODES) ? cnt[i] : 0;
    #pragma unroll
    for (int d = 32; d > 0; d >>= 1) v += __shfl_xor(v, d);
    if (lane == 0) ws[wid] = v;
    __syncthreads();
    if (tid == 0) partials[blockIdx.x] = ws[0] + ws[1] + ws[2] + ws[3];
}

__global__ __launch_bounds__(256) void scan_partials_scan(int* __restrict__ partials,
                                                          int* __restrict__ offsets) {
    __shared__ int ws[4];
    int tid = threadIdx.x, lane = tid & 63, wid = tid >> 6;
    int v = (tid < SCAN_BLOCKS) ? partials[tid] : 0;
    int x = v;
    #pragma unroll
    for (int d = 1; d < 64; d <<= 1) {
        int y = __shfl_up(x, d);
        if (lane >= d) x += y;
    }
    if (lane == 63) ws[wid] = x;
    __syncthreads();
    int woff = 0;
    for (int w = 0; w < wid; ++w) woff += ws[w];
    if (tid < SCAN_BLOCKS) partials[tid] = woff + x - v;   // exclusive
    if (tid == 255) offsets[N_NODES] = woff + x;           // grand total
}

__global__ __launch_bounds__(256) void scan_final(const int* __restrict__ cnt,
                                                  const int* __restrict__ partials,
                                                  int* __restrict__ offsets,
                                                  int* __restrict__ cursor) {
    __shared__ int ws[4];
    int tid = threadIdx.x, lane = tid & 63, wid = tid >> 6;
    int i = blockIdx.x * 256 + tid;
    int v = (i < N_NODES) ? cnt[i] : 0;
    int x = v;
    #pragma unroll
    for (int d = 1; d < 64; d <<= 1) {
        int y = __shfl_up(x, d);
        if (lane >= d) x += y;
    }
    if (lane == 63) ws[wid] = x;
    __syncthreads();
    int woff = 0;
    for (int w = 0; w < wid; ++w) woff += ws[w];
    if (i < N_NODES) {
        int off = partials[blockIdx.x] + woff + x - v;
        offsets[i] = off;
        cursor[i] = off;
    }
}

__global__ __launch_bounds__(256) void bucket_kernel(const int* __restrict__ row,
                                                     const int* __restrict__ col,
                                                     int* __restrict__ cursor,
                                                     int* __restrict__ srcbuf) {
    int e = blockIdx.x * 256 + threadIdx.x;
    if (e < N_EDGES) {
        int c = col[e];
        int p = atomicAdd(&cursor[c], 1);
        srcbuf[p] = row[e];
    }
}

// ---------------- W pre-transform + workspace zeroing ----------------
__global__ __launch_bounds__(256) void wsplit_kernel(const float* __restrict__ W1,
                                                     const float* __restrict__ W2,
                                                     ushort_t* __restrict__ wt,
                                                     int* __restrict__ cnt,
                                                     float* __restrict__ stats) {
    int idx = blockIdx.x * 256 + threadIdx.x;   // 0..32767
    for (int i = idx; i < N_NODES; i += 32768) cnt[i] = 0;
    if (idx < 512) stats[idx] = 0.f;
    int which = idx >> 14;
    int e = idx & 16383;                         // e = k*128 + n (coalesced read)
    int k = e >> 7, n = e & 127;
    float f = (which ? W2 : W1)[e];
    ushort_t h = f2bf(f);
    float fh = __uint_as_float((uint_t)h << 16);
    ushort_t l = f2bf(f - fh);
    size_t base = (size_t)which * 32768;
    wt[base + n * 128 + k] = h;                  // hi plane
    wt[base + 16384 + n * 128 + k] = l;          // lo plane
}

// ---------------- GEMM via MFMA: A bf16 (hi only), W split hi+lo ----------------
// Error: A rounding 2^-9 relative — same order as the bf16 output rounding already
// in the pipeline; W kept split (2^-18). 2 MFMAs/tile, A-LDS 8KB, total LDS 25KB.
// C written to the interleaved sup layout [node][batch][128] bf16.
template <bool BN>
__global__ __launch_bounds__(256) void gemm_mfma(const float* __restrict__ A,
                                                 const ushort_t* __restrict__ wt,
                                                 const float* __restrict__ stats,
                                                 const float* __restrict__ gamma,
                                                 const float* __restrict__ beta,
                                                 ushort_t* __restrict__ C) {
    __shared__ short lds[12288];  // Ah[0,4096) Wh[4096,8192) Wl[8192,12288)  (shorts)
    __shared__ float cs[256];     // scale[0:128], shift[128:256]
    int tid = threadIdx.x;
    long r0 = (long)blockIdx.x * 64;
    const float4* A4 = (const float4*)A;

    if (BN) {
        if (tid < 128) {
            float inv = 1.0f / (float)NROWS;
            float mean = stats[tid] * inv;
            float var = stats[128 + tid] * inv - mean * mean;
            float scale = gamma[tid] / sqrtf(var + BN_EPS);
            cs[tid] = scale;
            cs[128 + tid] = beta[tid] - mean * scale;
        }
        __syncthreads();
    }
    const float4* coef4 = (const float4*)cs;

    // stage A (bf16 hi only): 1024 tasks of one 16B block (8 elems)
    #pragma unroll
    for (int i = 0; i < 4; ++i) {
        int li = tid + i * 256;
        int r = li >> 4, j = li & 15;        // row 0..63, k-block 0..15
        long gr = r0 + r;
        float4 va = make_float4(0.f, 0.f, 0.f, 0.f), vb = va;
        if (gr < NROWS) { va = A4[gr * 32 + j * 2]; vb = A4[gr * 32 + j * 2 + 1]; }
        if (BN) {
            float4 sc = coef4[j * 2], sh = coef4[32 + j * 2];
            va.x = fmaxf(va.x * sc.x + sh.x, 0.f);
            va.y = fmaxf(va.y * sc.y + sh.y, 0.f);
            va.z = fmaxf(va.z * sc.z + sh.z, 0.f);
            va.w = fmaxf(va.w * sc.w + sh.w, 0.f);
            sc = coef4[j * 2 + 1]; sh = coef4[32 + j * 2 + 1];
            vb.x = fmaxf(vb.x * sc.x + sh.x, 0.f);
            vb.y = fmaxf(vb.y * sc.y + sh.y, 0.f);
            vb.z = fmaxf(vb.z * sc.z + sh.z, 0.f);
            vb.w = fmaxf(vb.w * sc.w + sh.w, 0.f);
        }
        bf16x8 vh;
        round4(va, vh, 0);
        round4(vb, vh, 4);
        *(bf16x8*)&lds[r * 64 + ((j ^ (r & 7)) * 8) % 64 + (j >= 8 ? 0 : 0)] = vh; // placeholder; replaced below
    }
    // NOTE: the staging store above must match the read indexing; use a simple
    // row-major layout with 16B-block XOR swizzle over 8 blocks (64 shorts/row... )
    // -- to keep correctness obvious we restage plainly:
    __syncthreads();
    // Correct staging (plain row-major, 8 k-blocks of 8 shorts per row half):
    #pragma unroll
    for (int i = 0; i < 4; ++i) {
        int li = tid + i * 256;
        int r = li >> 4, j = li & 15;
        long gr = r0 + r;
        float4 va = make_float4(0.f, 0.f, 0.f, 0.f), vb = va;
        if (gr < NROWS) { va = A4[gr * 32 + j * 2]; vb = A4[gr * 32 + j * 2 + 1]; }
        if (BN) {
            float4 sc = coef4[j * 2], sh = coef4[32 + j * 2];
            va.x = fmaxf(va.x * sc.x + sh.x, 0.f);
            va.y = fmaxf(va.y * sc.y + sh.y, 0.f);
            va.z = fmaxf(va.z * sc.z + sh.z, 0.f);
            va.w = fmaxf(va.w * sc.w + sh.w, 0.f);
            sc = coef4[j * 2 + 1]; sh = coef4[32 + j * 2 + 1];
            vb.x = fmaxf(vb.x * sc.x + sh.x, 0.f);
            vb.y = fmaxf(vb.y * sc.y + sh.y, 0.f);
            vb.z = fmaxf(vb.z * sc.z + sh.z, 0.f);
            vb.w = fmaxf(vb.w * sc.w + sh.w, 0.f);
        }
        bf16x8 vh;
        round4(va, vh, 0);
        round4(vb, vh, 4);
        // A layout: row r (0..63) x 16 k-blocks of 8 shorts, XOR-swizzled by row
        *(bf16x8*)&lds[0 + r * 64 /*shorts? need 128*/] = vh;
    }
    __syncthreads();

    // (unreachable placeholder guard — real kernel below)
    // This template instant is never compiled-in; see gemm_mfma2.
}

// ---------------- GEMM (actual): A bf16 hi-only in LDS, W split hi+lo in LDS ----------------
template <bool BN>
__global__ __launch_bounds__(256) void gemm_mfma2(const float* __restrict__ A,
                                                  const ushort_t* __restrict__ wt,
                                                  const float* __restrict__ stats,
                                                  const float* __restrict__ gamma,
                                                  const float* __restrict__ beta,
                                                  ushort_t* __restrict__ C) {
    __shared__ short lds[24576];  // Ah[0,8192) Wh[8192,16384) Wl[16384,24576)
    __shared__ float cs[256];     // scale[0:128], shift[128:256]
    int tid = threadIdx.x;
    long r0 = (long)blockIdx.x * 64;
    const float4* A4 = (const float4*)A;

    if (BN) {
        if (tid < 128) {
            float inv = 1.0f / (float)NROWS;
            float mean = stats[tid] * inv;
            float var = stats[128 + tid] * inv - mean * mean;
            float scale = gamma[tid] / sqrtf(var + BN_EPS);
            cs[tid] = scale;
            cs[128 + tid] = beta[tid] - mean * scale;
        }
        __syncthreads();
    }
    const float4* coef4 = (const float4*)cs;

    // stage A (bf16 hi only): row r x 16 k-blocks of 8 shorts, XOR swizzle (j ^ (r&15))
    #pragma unroll
    for (int i = 0; i < 4; ++i) {
        int li = tid + i * 256;
        int r = li >> 4, j = li & 15;        // row 0..63, k-block 0..15
        long gr = r0 + r;
        float4 va = make_float4(0.f, 0.f, 0.f, 0.f), vb = va;
        if (gr < NROWS) { va = A4[gr * 32 + j * 2]; vb = A4[gr * 32 + j * 2 + 1]; }
        if (BN) {
            float4 sc = coef4[j * 2], sh = coef4[32 + j * 2];
            va.x = fmaxf(va.x * sc.x + sh.x, 0.f);
            va.y = fmaxf(va.y * sc.y + sh.y, 0.f);
            va.z = fmaxf(va.z * sc.z + sh.z, 0.f);
            va.w = fmaxf(va.w * sc.w + sh.w, 0.f);
            sc = coef4[j * 2 + 1]; sh = coef4[32 + j * 2 + 1];
            vb.x = fmaxf(vb.x * sc.x + sh.x, 0.f);
            vb.y = fmaxf(vb.y * sc.y + sh.y, 0.f);
            vb.z = fmaxf(vb.z * sc.z + sh.z, 0.f);
            vb.w = fmaxf(vb.w * sc.w + sh.w, 0.f);
        }
        bf16x8 vh;
        round4(va, vh, 0);
        round4(vb, vh, 4);
        *(bf16x8*)&lds[r * 128 + ((j ^ (r & 15)) * 8)] = vh;
    }

    int w = tid >> 6, l = tid & 63;
    int m = l & 15, q = l >> 4;
    for (int half = 0; half < 2; ++half) {
        __syncthreads();
        // stage W-split half: 2048 tasks (plane, n_loc, k-block)
        #pragma unroll
        for (int i = 0; i < 8; ++i) {
            int li = tid + i * 256;
            int p = li >> 10;                 // 0=hi 1=lo
            int rest = li & 1023;
            int nl = rest >> 4, j = rest & 15;
            bf16x8 v = *(const bf16x8*)&wt[(size_t)p * 16384 + (half * 64 + nl) * 128 + j * 8];
            *(bf16x8*)&lds[8192 + p * 8192 + nl * 128 + ((j ^ (nl & 15)) * 8)] = v;
        }
        __syncthreads();

        f32x4 acc[4] = {};
        #pragma unroll
        for (int s = 0; s < 4; ++s) {
            int x = (s * 4 + q) ^ m;
            bf16x8 ah = *(const bf16x8*)&lds[(w * 16 + m) * 128 + x * 8];
            #pragma unroll
            for (int c = 0; c < 4; ++c) {
                int boff = 8192 + (c * 16 + m) * 128 + x * 8;
                bf16x8 bh = *(const bf16x8*)&lds[boff];
                bf16x8 bl = *(const bf16x8*)&lds[8192 + boff];
                acc[c] = __builtin_amdgcn_mfma_f32_16x16x32_bf16(ah, bl, acc[c], 0, 0, 0);
                acc[c] = __builtin_amdgcn_mfma_f32_16x16x32_bf16(ah, bh, acc[c], 0, 0, 0);
            }
        }

        // write C (bf16, interleaved rows): row gr -> (node*2 + b)*128
        #pragma unroll
        for (int c = 0; c < 4; ++c) {
            #pragma unroll
            for (int r = 0; r < 4; ++r) {
                long gr = r0 + w * 16 + q * 4 + r;
                if (gr < NROWS) {
                    int b = gr >= N_NODES;
                    long node = gr - (long)b * N_NODES;
                    C[(node * 2 + b) * 128 + half * 64 + c * 16 + m] = f2bf(acc[c][r]);
                }
            }
        }
    }
}

// ---------------- Aggregate (round-10 verified hot loop; interleaved sup rows) ----------------
__global__ __launch_bounds__(256) void aggregate_bf16(const ushort_t* __restrict__ sup,
                                                      const int* __restrict__ offsets,
                                                      const int* __restrict__ srcbuf,
                                                      float* __restrict__ agg) {
    int lane = threadIdx.x & 63;
    int wid = threadIdx.x >> 6;
    int node = blockIdx.x * 4 + wid;        // 12500*4 = 50000 exactly
    int s = lane >> 5;       // half-wave id
    int l32 = lane & 31;
    int beg = offsets[node], end = offsets[node + 1];
    const ushort4* sb = (const ushort4*)sup;   // row r: [r*64, +32)=batch0, [+32, +64)=batch1
    float4 a0 = make_float4(0.f, 0.f, 0.f, 0.f);
    float4 a1 = make_float4(0.f, 0.f, 0.f, 0.f);
    for (int i = beg; i < end; i += 64) {
        int m = end - i; if (m > 64) m = 64;
        int idx = (i + lane < end) ? srcbuf[i + lane] : 0;  // coalesced index load
        int tmax = (m + 1) >> 1;
        #pragma unroll 2
        for (int t = 0; t < tmax; ++t) {
            int j = 2 * t + s;
            int r = __shfl(idx, j & 63);
            ushort4 u0 = sb[(size_t)r * 64 + l32];        // batch 0 half-row
            ushort4 u1 = sb[(size_t)r * 64 + 32 + l32];   // batch 1 half-row
            if (j < m) {
                float4 f0 = bf4_to_f4(u0);
                float4 f1 = bf4_to_f4(u1);
                a0.x += f0.x; a0.y += f0.y; a0.z += f0.z; a0.w += f0.w;
                a1.x += f1.x; a1.y += f1.y; a1.z += f1.z; a1.w += f1.w;
            }
        }
    }
    a0.x += __shfl_xor(a0.x, 32); a0.y += __shfl_xor(a0.y, 32);
    a0.z += __shfl_xor(a0.z, 32); a0.w += __shfl_xor(a0.w, 32);
    a1.x += __shfl_xor(a1.x, 32); a1.y += __shfl_xor(a1.y, 32);
    a1.z += __shfl_xor(a1.z, 32); a1.w += __shfl_xor(a1.w, 32);
    float4* ag = (float4*)agg;
    if (s == 0) ag[(size_t)node * 32 + l32] = a0;                       // batch 0 row
    else        ag[(size_t)(N_NODES + node) * 32 + l32] = a1;           // batch 1 row
}

// ---------------- BatchNorm stats (over raw agg) ----------------

__global__ __launch_bounds__(256) void bn_stats_kernel(const float* __restrict__ h,
                                                       float* __restrict__ stats) {
    __shared__ float ls[256], ls2[256];
    int tid = threadIdx.x;
    int f = tid & 127, half = tid >> 7;
    float s = 0.f, s2 = 0.f;
    for (int row = blockIdx.x * 2 + half; row < NROWS; row += gridDim.x * 2) {
        float v = h[(size_t)row * FDIM + f];
        s += v; s2 += v * v;
    }
    ls[tid] = s; ls2[tid] = s2;
    __syncthreads();
    if (tid < 128) {
        atomicAdd(&stats[f], ls[tid] + ls[tid + 128]);
        atomicAdd(&stats[128 + f], ls2[tid] + ls2[tid + 128]);
    }
}

// ---------------- Layer 3: fused BN+ReLU GEMV (coef in-block) + CSR gather ----------------
__global__ __launch_bounds__(256) void gemv_bn_kernel(const float* __restrict__ h,
                                                      const float* __restrict__ stats,
                                                      const float* __restrict__ gamma,
                                                      const float* __restrict__ beta,
                                                      const float* __restrict__ W3,
                                                      float* __restrict__ sup3) {
    __shared__ float cs[256];
    int tid = threadIdx.x;
    if (tid < 128) {
        float inv = 1.0f / (float)NROWS;
        float mean = stats[tid] * inv;
        float var = stats[128 + tid] * inv - mean * mean;
        float scale = gamma[tid] / sqrtf(var + BN_EPS);
        cs[tid] = scale;
        cs[128 + tid] = beta[tid] - mean * scale;
    }
    __syncthreads();
    int lane = tid & 63, wid = tid >> 6;
    float2 w  = ((const float2*)W3)[lane];
    float2 sc = ((const float2*)cs)[lane];
    float2 sh = ((const float2*)(cs + 128))[lane];
    #pragma unroll
    for (int r = 0; r < 4; ++r) {
        long gw = (long)blockIdx.x * 16 + wid * 4 + r;   // 6250*16 = 100000 exactly
        float2 v = ((const float2*)h)[(size_t)gw * 64 + lane];
        v.x = fmaxf(v.x * sc.x + sh.x, 0.f);
        v.y = fmaxf(v.y * sc.y + sh.y, 0.f);
        float s = v.x * w.x + v.y * w.y;
        #pragma unroll
        for (int d = 32; d > 0; d >>= 1) s += __shfl_xor(s, d);
        if (lane == 0) sup3[gw] = s;
    }
}

// out[b,n] = b3 + sum over CSR in-edges of sup3[b, src].
__global__ __launch_bounds__(256) void gather_out_kernel(const int* __restrict__ offsets,
                                                         const int* __restrict__ srcbuf,
                                                         const float* __restrict__ sup3,
                                                         const float* __restrict__ b3,
                                                         float* __restrict__ out) {
    int n = blockIdx.x * 256 + threadIdx.x;
    if (n >= N_NODES) return;
    int beg = offsets[n], end = offsets[n + 1];
    float s0 = 0.f, s1 = 0.f;
    for (int i = beg; i < end; ++i) {
        int r = srcbuf[i];
        s0 += sup3[r];
        s1 += sup3[N_NODES + r];
    }
    float b = b3[0];
    out[n] = s0 + b;
    out[N_NODES + n] = s1 + b;
}

// ---------------- launch ----------------

extern "C" void kernel_launch(void* const* d_in, const int* in_sizes, int n_in,
                              void* d_out, int out_size, void* d_ws, size_t ws_size,
                              hipStream_t stream) {
    const float* x      = (const float*)d_in[0];
    const int*   ei     = (const int*)d_in[1];
    const float* W1     = (const float*)d_in[2];
    // d_in[3] = b1: per-feature bias before BN cancels exactly (shifts mean identically)
    const float* W2     = (const float*)d_in[4];
    // d_in[5] = b2: same cancellation
    const float* W3     = (const float*)d_in[6];
    const float* b3     = (const float*)d_in[7];
    const float* gamma1 = (const float*)d_in[8];
    const float* beta1  = (const float*)d_in[9];
    const float* gamma2 = (const float*)d_in[10];
    const float* beta2  = (const float*)d_in[11];
    const int* rowp = ei;             // edge_index[0]
    const int* colp = ei + N_EDGES;   // edge_index[1]

    ushort_t* sup   = (ushort_t*)d_ws;              // 12.8M bf16 (25.6 MB), [node][batch][128]
    float* agg      = (float*)(sup + 12800000);     // 12.8M floats (51.2 MB), [b*N+node][128]
    float* sup3     = agg + 12800000;               // 100k floats
    ushort_t* wt    = (ushort_t*)(sup3 + 100000);   // 65536 ushorts: W1/W2 split planes
    float* stats    = (float*)(wt + 65536);         // 512 floats
    int*   cnt      = (int*)(stats + 512);          // 50000
    int*   offsets  = cnt + N_NODES;                // 50001
    int*   cursor   = offsets + N_NODES + 1;        // 50000
    int*   srcbuf   = cursor + N_NODES;             // 800000
    int*   scanp    = srcbuf + N_EDGES;             // 196
    float* out      = (float*)d_out;

    // W split/transpose + cnt/stats zeroing, then CSR build (round-10 3-phase scan)
    wsplit_kernel     <<<128,         256, 0, stream>>>(W1, W2, wt, cnt, stats);
    hist_kernel       <<<3125,        256, 0, stream>>>(colp, cnt);
    scan_partials_sum <<<SCAN_BLOCKS, 256, 0, stream>>>(cnt, scanp);
    scan_partials_scan<<<1,           256, 0, stream>>>(scanp, offsets);
    scan_final        <<<SCAN_BLOCKS, 256, 0, stream>>>(cnt, scanp, offsets, cursor);
    bucket_kernel     <<<3125,        256, 0, stream>>>(rowp, colp, cursor, srcbuf);

    // layer 1: sup = x@W1 (A-hi MFMA, W split), agg = A·sup, stats
    gemm_mfma2<false><<<1563,  256, 0, stream>>>(x, wt, nullptr, nullptr, nullptr, sup);
    aggregate_bf16   <<<12500, 256, 0, stream>>>(sup, offsets, srcbuf, agg);
    bn_stats_kernel  <<<512,   256, 0, stream>>>(agg, stats);

    // layer 2: sup = relu(bn1(agg))@W2 (coef in-block), agg = A·sup, stats
    gemm_mfma2<true> <<<1563,  256, 0, stream>>>(agg, wt + 32768, stats, gamma1, beta1, sup);
    aggregate_bf16   <<<12500, 256, 0, stream>>>(sup, offsets, srcbuf, agg);
    bn_stats_kernel  <<<512,   256, 0, stream>>>(agg, stats + 256);

    // layer 3: sup3 = relu(bn2(agg))@W3 (coef in-block), out = A·sup3 + b3 (CSR gather)
    gemv_bn_kernel   <<<6250, 256, 0, stream>>>(agg, stats + 256, gamma2, beta2, W3, sup3);
    gather_out_kernel<<<SCAN_BLOCKS, 256, 0, stream>>>(offsets, srcbuf, sup3, b3, out);
}